// Round 9
// baseline (509.502 us; speedup 1.0000x reference)
//
#include <hip/hip_runtime.h>
#include <hip/hip_bf16.h>
#include <stdint.h>

// ---------------------------------------------------------------------------
// MHA forward, bf16 MFMA path (gfx950).  B=1, S=4096, D=1024, H=16, HD=64.
//   1. preprocess: cast x->bf16 + transpose-cast Wq|Wk|Wv, Wo
//   2. gemm_qkv: QK = xb @ Wt^T (stride 2048, Q pre-scaled 0.125*log2e);
//      V scatter-stored transposed to Vt[1024][4096]
//   3. flash_attn: 1024 blocks (4/CU), XCD-local heads (2 heads/XCD so K/V
//      fit in 4MB L2), balanced bijective q-tile map, k-split waves
//      (32 keys/wave), K/V/Q frags global->VGPR with register ping-pong,
//      key-permuted S^T so P packs into K=32 A-frags, chunked cross-wave
//      O reduction (21.5 KB LDS, K-loop barrier-free)
//   4. gemm_out: out = Ctx @ Wot^T + bo (fp32), 64x128 tiles (512 blocks)
// ---------------------------------------------------------------------------

typedef __bf16 bf16;
typedef __bf16 bf16x4 __attribute__((ext_vector_type(4)));
typedef __bf16 bf16x8 __attribute__((ext_vector_type(8)));
typedef float  f32x4  __attribute__((ext_vector_type(4)));

#define MFMA32(a, b, c) __builtin_amdgcn_mfma_f32_16x16x32_bf16((a), (b), (c), 0, 0, 0)

static constexpr int S_LEN  = 4096;
static constexpr int DMODEL = 1024;
static constexpr int HDIM   = 64;
static constexpr int LDQK   = 2048;

#define GLOAD_LDS16(g, l)                                                      \
  __builtin_amdgcn_global_load_lds((__attribute__((address_space(1))) void*)(g), \
                                   (__attribute__((address_space(3))) void*)(l), 16, 0, 0)

// ------------- fused preprocess: cast x + 4 weight transposes --------------
__global__ __launch_bounds__(256) void preprocess(const float* __restrict__ x,
                                                  const float* __restrict__ Wq,
                                                  const float* __restrict__ Wk,
                                                  const float* __restrict__ Wv,
                                                  const float* __restrict__ Wo,
                                                  bf16* __restrict__ xb,
                                                  bf16* __restrict__ Wt,
                                                  bf16* __restrict__ Wot) {
  __shared__ float tile[64][65];
  const int t = threadIdx.x, b = blockIdx.x;
  if (b < 1024) {
#pragma unroll
    for (int i = 0; i < 4; i++) {
      int idx = b * 1024 + i * 256 + t;
      float4 v = ((const float4*)x)[idx];
      bf16x4 o;
      o[0] = (bf16)v.x; o[1] = (bf16)v.y; o[2] = (bf16)v.z; o[3] = (bf16)v.w;
      ((bf16x4*)xb)[idx] = o;
    }
    return;
  }
  const int id = b - 1024;
  const int wsel = id >> 8;
  const int t2 = id & 255;
  const int kb = (t2 & 15) * 64, nb = (t2 >> 4) * 64;
  const float* src = (wsel == 0) ? Wq : (wsel == 1) ? Wk : (wsel == 2) ? Wv : Wo;
  bf16* dst = (wsel < 3) ? (Wt + (size_t)wsel * 1024 * 1024) : Wot;
#pragma unroll
  for (int i = 0; i < 16; i++) {
    int idx = t + i * 256;
    int r = idx >> 6, c = idx & 63;
    tile[r][c] = src[(size_t)(kb + r) * 1024 + nb + c];
  }
  __syncthreads();
#pragma unroll
  for (int i = 0; i < 16; i++) {
    int idx = t + i * 256;
    int cc = idx >> 6, rr = idx & 63;
    dst[(size_t)(nb + cc) * 1024 + kb + rr] = (bf16)tile[rr][cc];
  }
}

// ------------------- gemm_qkv: 128x128 tile, K=1024, BK=32 -----------------
__global__ __launch_bounds__(256) void gemm_qkv(const bf16* __restrict__ A,
                                                const bf16* __restrict__ Bt,
                                                bf16* __restrict__ QK,
                                                bf16* __restrict__ Vt) {
  __shared__ bf16 lsA[128 * 32];
  __shared__ bf16 lsB[128 * 32];
  const int tid = threadIdx.x, w = tid >> 6, lane = tid & 63;
  const int l15 = lane & 15, quad = lane >> 4;
  const int m0 = blockIdx.x * 128, n0 = blockIdx.y * 128;
  const int wm = (w >> 1) * 64, wn = (w & 1) * 64;
  const int rowA = lane >> 2;
  const int colk = (lane & 3) * 8;

  f32x4 acc[4][4] = {};

  for (int k0 = 0; k0 < 1024; k0 += 32) {
    __syncthreads();
#pragma unroll
    for (int i = 0; i < 2; i++) {
      int s = w * 2 + i;
      const bf16* ga = A + (size_t)(m0 + s * 16 + rowA) * 1024 + k0 + colk;
      GLOAD_LDS16(ga, lsA + s * 512);
      const bf16* gb = Bt + (size_t)(n0 + s * 16 + rowA) * 1024 + k0 + colk;
      GLOAD_LDS16(gb, lsB + s * 512);
    }
    __syncthreads();

    bf16x8 af[4], bfr[4];
#pragma unroll
    for (int r = 0; r < 4; r++)
      af[r] = *(const bf16x8*)(lsA + (wm + r * 16 + l15) * 32 + quad * 8);
#pragma unroll
    for (int c = 0; c < 4; c++)
      bfr[c] = *(const bf16x8*)(lsB + (wn + c * 16 + l15) * 32 + quad * 8);
#pragma unroll
    for (int r = 0; r < 4; r++)
#pragma unroll
      for (int c = 0; c < 4; c++)
        acc[r][c] = MFMA32(af[r], bfr[c], acc[r][c]);
  }

  if (n0 < 2048) {
#pragma unroll
    for (int r = 0; r < 4; r++) {
#pragma unroll
      for (int c = 0; c < 4; c++) {
        int col = n0 + wn + c * 16 + l15;
        float scale = (col < 1024) ? 0.18033688f : 1.0f;  // 0.125*log2e on Q
#pragma unroll
        for (int e = 0; e < 4; e++) {
          int row = m0 + wm + r * 16 + quad * 4 + e;
          QK[(size_t)row * LDQK + col] = (bf16)(acc[r][c][e] * scale);
        }
      }
    }
  } else {
#pragma unroll
    for (int r = 0; r < 4; r++) {
#pragma unroll
      for (int c = 0; c < 4; c++) {
        int vcol = (n0 - 2048) + wn + c * 16 + l15;
        int row0 = m0 + wm + r * 16 + quad * 4;
        bf16x4 pk;
#pragma unroll
        for (int e = 0; e < 4; e++) pk[e] = (bf16)acc[r][c][e];
        *(bf16x4*)(Vt + (size_t)vcol * S_LEN + row0) = pk;
      }
    }
  }
}

// ----------------------------- flash attention -----------------------------
// 1024 blocks, one 64-q tile each, 4 blocks/CU.
//   head = (i&7) + 8*((i>>3)&1)   -> each XCD holds only 2 heads' K/V in L2
//   qb   = qt<32 ? qt : 95-qt     -> bijective; per-CU tile-work 67±1
// 128-key tiles, 32 keys/wave; K/V/Q frags global->VGPR, register ping-pong.
__global__ __launch_bounds__(256, 4) void flash_attn(const bf16* __restrict__ QK,
                                                     const bf16* __restrict__ Vt,
                                                     bf16* __restrict__ Ctx) {
  __shared__ float Obuf[4][16][68];   // 17.4 KB: per-wave partial O, one qg chunk
  __shared__ float Lbuf[4][4][64];    // 4 KB
  const int tid = threadIdx.x, w = tid >> 6, lane = tid & 63;
  const int l15 = lane & 15, quad = lane >> 4;
  const int i = blockIdx.x;
  const int head = (i & 7) + 8 * ((i >> 3) & 1);
  const int qt_raw = i >> 4;
  const int qb = (qt_raw < 32) ? qt_raw : (95 - qt_raw);
  const int hq = head * HDIM;
  const int krow0 = w * 32 + ((l15 >> 2) << 3) + (l15 & 3);  // permuted key row

  const int T = (qb >> 1) + 1;              // 128-key tiles

  // Q frags (B-operand): q = qb*64 + qg*16 + l15, d = kk*32 + quad*8 + j
  bf16x8 qf[4][2];
#pragma unroll
  for (int qg = 0; qg < 4; qg++)
#pragma unroll
    for (int kk = 0; kk < 2; kk++)
      qf[qg][kk] = *(const bf16x8*)(QK + (size_t)(qb * 64 + qg * 16 + l15) * LDQK +
                                    hq + kk * 32 + quad * 8);

  f32x4 oacc[4][4] = {};
  float lsum[4] = {0.f, 0.f, 0.f, 0.f};

  auto load_k = [&](int j, bf16x8 (&kf)[2][2]) {
#pragma unroll
    for (int c = 0; c < 2; c++)
#pragma unroll
      for (int kk = 0; kk < 2; kk++)
        kf[c][kk] = *(const bf16x8*)(QK + (size_t)(j * 128 + krow0 + 4 * c) * LDQK +
                                     DMODEL + hq + kk * 32 + quad * 8);
  };
  auto load_v = [&](int j, bf16x8 (&vf)[4]) {
#pragma unroll
    for (int dg = 0; dg < 4; dg++)
      vf[dg] = *(const bf16x8*)(Vt + (size_t)(hq + dg * 16 + l15) * S_LEN +
                                j * 128 + w * 32 + quad * 8);
  };
  auto compute = [&](int j, bf16x8 (&kf)[2][2], bf16x8 (&vf)[4]) {
    // S^T = K Q^T : C row = key-slot quad*4+e (matrix c), col = q = l15
    f32x4 sacc[2][4] = {};
#pragma unroll
    for (int kk = 0; kk < 2; kk++)
#pragma unroll
      for (int c = 0; c < 2; c++)
#pragma unroll
        for (int qg = 0; qg < 4; qg++)
          sacc[c][qg] = MFMA32(kf[c][kk], qf[qg][kk], sacc[c][qg]);

    bf16x8 pfr[4];
    if (j == T - 1) {
      const int kb0 = j * 128 + w * 32 + quad * 8;   // + 4c + e = actual key
#pragma unroll
      for (int qg = 0; qg < 4; qg++) {
        const int qrow = qb * 64 + qg * 16 + l15;
        bf16x8 pb;
#pragma unroll
        for (int c = 0; c < 2; c++)
#pragma unroll
          for (int e = 0; e < 4; e++) {
            float s = sacc[c][qg][e];
            if (kb0 + 4 * c + e > qrow) s = -1e30f;
            float pv = __builtin_amdgcn_exp2f(s);
            lsum[qg] += pv;
            pb[c * 4 + e] = (bf16)pv;
          }
        pfr[qg] = pb;
      }
    } else {
#pragma unroll
      for (int qg = 0; qg < 4; qg++) {
        bf16x8 pb;
#pragma unroll
        for (int c = 0; c < 2; c++)
#pragma unroll
          for (int e = 0; e < 4; e++) {
            float pv = __builtin_amdgcn_exp2f(sacc[c][qg][e]);
            lsum[qg] += pv;
            pb[c * 4 + e] = (bf16)pv;
          }
        pfr[qg] = pb;
      }
    }

    // O += P V  (K=32, P direct from registers)
#pragma unroll
    for (int qg = 0; qg < 4; qg++)
#pragma unroll
      for (int dg = 0; dg < 4; dg++)
        oacc[qg][dg] = MFMA32(pfr[qg], vf[dg], oacc[qg][dg]);
  };

  bf16x8 kfA[2][2], vfA[4], kfB[2][2], vfB[4];
  load_k(0, kfA); load_v(0, vfA);
  for (int j = 0; j < T; j += 2) {
    if (j + 1 < T) { load_k(j + 1, kfB); load_v(j + 1, vfB); }
    compute(j, kfA, vfA);
    if (j + 2 < T) { load_k(j + 2, kfA); load_v(j + 2, vfA); }
    if (j + 1 < T) compute(j + 1, kfB, vfB);
  }

  // ---- chunked cross-wave reduction: one qg (16 q-rows) at a time ----
#pragma unroll
  for (int qg = 0; qg < 4; qg++)
    Lbuf[w][quad][qg * 16 + l15] = lsum[qg];

  const int row = tid >> 4;               // 0..15 (local q within chunk)
  const int col = (tid & 15) * 4;         // 0..60 (d within head)
  for (int qg = 0; qg < 4; qg++) {
#pragma unroll
    for (int dg = 0; dg < 4; dg++)
#pragma unroll
      for (int e = 0; e < 4; e++)
        Obuf[w][quad * 4 + e][dg * 16 + l15] = oacc[qg][dg][e];
    __syncthreads();                      // writes visible
    f32x4 os = {};
#pragma unroll
    for (int ww = 0; ww < 4; ww++)
      os += *(const f32x4*)&Obuf[ww][row][col];
    float lr = 0.f;
#pragma unroll
    for (int ww = 0; ww < 4; ww++)
#pragma unroll
      for (int qq = 0; qq < 4; qq++)
        lr += Lbuf[ww][qq][qg * 16 + row];
    const float linv = 1.f / lr;
    bf16x4 ob;
#pragma unroll
    for (int e2 = 0; e2 < 4; e2++) ob[e2] = (bf16)(os[e2] * linv);
    *(bf16x4*)(Ctx + (size_t)(qb * 64 + qg * 16 + row) * DMODEL + hq + col) = ob;
    __syncthreads();                      // reads done before next chunk
  }
}

// ---------------- gemm_out: 64x128 tile, K=1024 -> 512 blocks --------------
__global__ __launch_bounds__(256) void gemm_out(const bf16* __restrict__ A,
                                                const bf16* __restrict__ Bt,
                                                float* __restrict__ C,
                                                const float* __restrict__ bias) {
  __shared__ bf16 lsA[64 * 32];
  __shared__ bf16 lsB[128 * 32];
  const int tid = threadIdx.x, w = tid >> 6, lane = tid & 63;
  const int l15 = lane & 15, quad = lane >> 4;
  const int m0 = blockIdx.x * 64, n0 = blockIdx.y * 128;
  const int wm = (w >> 1) * 32, wn = (w & 1) * 64;
  const int rowA = lane >> 2;
  const int colk = (lane & 3) * 8;

  f32x4 acc[2][4] = {};

  for (int k0 = 0; k0 < 1024; k0 += 32) {
    __syncthreads();
#pragma unroll
    for (int i = 0; i < 3; i++) {
      int s = w * 3 + i;
      if (s < 4) {
        const bf16* ga = A + (size_t)(m0 + s * 16 + rowA) * 1024 + k0 + colk;
        GLOAD_LDS16(ga, lsA + s * 512);
      } else {
        const bf16* gb = Bt + (size_t)(n0 + (s - 4) * 16 + rowA) * 1024 + k0 + colk;
        GLOAD_LDS16(gb, lsB + (s - 4) * 512);
      }
    }
    __syncthreads();

    bf16x8 af[2], bfr[4];
#pragma unroll
    for (int r = 0; r < 2; r++)
      af[r] = *(const bf16x8*)(lsA + (wm + r * 16 + l15) * 32 + quad * 8);
#pragma unroll
    for (int c = 0; c < 4; c++)
      bfr[c] = *(const bf16x8*)(lsB + (wn + c * 16 + l15) * 32 + quad * 8);
#pragma unroll
    for (int r = 0; r < 2; r++)
#pragma unroll
      for (int c = 0; c < 4; c++)
        acc[r][c] = MFMA32(af[r], bfr[c], acc[r][c]);
  }

#pragma unroll
  for (int r = 0; r < 2; r++) {
#pragma unroll
    for (int c = 0; c < 4; c++) {
      int col = n0 + wn + c * 16 + l15;
#pragma unroll
      for (int e = 0; e < 4; e++) {
        int row = m0 + wm + r * 16 + quad * 4 + e;
        C[(size_t)row * 1024 + col] = acc[r][c][e] + bias[col];
      }
    }
  }
}

// ------------------------------- launcher ----------------------------------
extern "C" void kernel_launch(void* const* d_in, const int* in_sizes, int n_in,
                              void* d_out, int out_size, void* d_ws, size_t ws_size,
                              hipStream_t stream) {
  const float* x  = (const float*)d_in[0];
  const float* Wq = (const float*)d_in[1];
  const float* Wk = (const float*)d_in[2];
  const float* Wv = (const float*)d_in[3];
  const float* Wo = (const float*)d_in[4];
  const float* bo = (const float*)d_in[5];

  char* ws = (char*)d_ws;                    // 48 MB total
  bf16* xb  = (bf16*)(ws);                   // 8 MB  [4096][1024]
  bf16* Wt  = (bf16*)(ws + (8u  << 20));     // 6 MB  [3072][1024]
  bf16* Wot = (bf16*)(ws + (14u << 20));     // 2 MB  [1024][1024]
  bf16* QK  = (bf16*)(ws + (16u << 20));     // 16 MB [4096][2048]
  bf16* Vt  = (bf16*)(ws + (32u << 20));     // 8 MB  [1024][4096]
  bf16* Ctx = (bf16*)(ws + (40u << 20));     // 8 MB  [4096][1024]

  preprocess<<<2048, 256, 0, stream>>>(x, Wq, Wk, Wv, Wo, xb, Wt, Wot);
  gemm_qkv<<<dim3(32, 24), 256, 0, stream>>>(xb, Wt, QK, Vt);
  flash_attn<<<1024, 256, 0, stream>>>(QK, Vt, Ctx);
  gemm_out<<<dim3(64, 8), 256, 0, stream>>>(Ctx, Wot, (float*)d_out, bo);
}

// Round 10
// 205.175 us; speedup vs baseline: 2.4833x; 2.4833x over previous
//
#include <hip/hip_runtime.h>
#include <hip/hip_bf16.h>
#include <stdint.h>

// ---------------------------------------------------------------------------
// MHA forward, bf16 MFMA path (gfx950).  B=1, S=4096, D=1024, H=16, HD=64.
//   1. preprocess: cast x->bf16 + transpose-cast Wq|Wk|Wv, Wo
//   2. gemm_qkv: QK = xb @ Wt^T (stride 2048, Q pre-scaled 0.125*log2e);
//      V scatter-stored transposed to Vt[1024][4096]
//   3. flash_attn: 1024 blocks (4/CU at 128 VGPR), XCD-local heads, balanced
//      bijective q-tile map, k-split waves (32 keys/wave), K/V/Q frags
//      global->VGPR with register ping-pong, key-permuted S^T so P packs
//      into K=32 A-frags, chunked cross-wave O reduction (21.5 KB LDS).
//      NOTE: __launch_bounds__(256,2) NOT (256,4) — the latter caps the
//      unified VGPR+AGPR file at 128 and spills 900 MB to scratch (round 9).
//   4. gemm_out: out = Ctx @ Wot^T + bo (fp32), 64x128 tiles (512 blocks)
// ---------------------------------------------------------------------------

typedef __bf16 bf16;
typedef __bf16 bf16x4 __attribute__((ext_vector_type(4)));
typedef __bf16 bf16x8 __attribute__((ext_vector_type(8)));
typedef float  f32x4  __attribute__((ext_vector_type(4)));

#define MFMA32(a, b, c) __builtin_amdgcn_mfma_f32_16x16x32_bf16((a), (b), (c), 0, 0, 0)

static constexpr int S_LEN  = 4096;
static constexpr int DMODEL = 1024;
static constexpr int HDIM   = 64;
static constexpr int LDQK   = 2048;

#define GLOAD_LDS16(g, l)                                                      \
  __builtin_amdgcn_global_load_lds((__attribute__((address_space(1))) void*)(g), \
                                   (__attribute__((address_space(3))) void*)(l), 16, 0, 0)

// ------------- fused preprocess: cast x + 4 weight transposes --------------
__global__ __launch_bounds__(256) void preprocess(const float* __restrict__ x,
                                                  const float* __restrict__ Wq,
                                                  const float* __restrict__ Wk,
                                                  const float* __restrict__ Wv,
                                                  const float* __restrict__ Wo,
                                                  bf16* __restrict__ xb,
                                                  bf16* __restrict__ Wt,
                                                  bf16* __restrict__ Wot) {
  __shared__ float tile[64][65];
  const int t = threadIdx.x, b = blockIdx.x;
  if (b < 1024) {
#pragma unroll
    for (int i = 0; i < 4; i++) {
      int idx = b * 1024 + i * 256 + t;
      float4 v = ((const float4*)x)[idx];
      bf16x4 o;
      o[0] = (bf16)v.x; o[1] = (bf16)v.y; o[2] = (bf16)v.z; o[3] = (bf16)v.w;
      ((bf16x4*)xb)[idx] = o;
    }
    return;
  }
  const int id = b - 1024;
  const int wsel = id >> 8;
  const int t2 = id & 255;
  const int kb = (t2 & 15) * 64, nb = (t2 >> 4) * 64;
  const float* src = (wsel == 0) ? Wq : (wsel == 1) ? Wk : (wsel == 2) ? Wv : Wo;
  bf16* dst = (wsel < 3) ? (Wt + (size_t)wsel * 1024 * 1024) : Wot;
#pragma unroll
  for (int i = 0; i < 16; i++) {
    int idx = t + i * 256;
    int r = idx >> 6, c = idx & 63;
    tile[r][c] = src[(size_t)(kb + r) * 1024 + nb + c];
  }
  __syncthreads();
#pragma unroll
  for (int i = 0; i < 16; i++) {
    int idx = t + i * 256;
    int cc = idx >> 6, rr = idx & 63;
    dst[(size_t)(nb + cc) * 1024 + kb + rr] = (bf16)tile[rr][cc];
  }
}

// ------------------- gemm_qkv: 128x128 tile, K=1024, BK=32 -----------------
__global__ __launch_bounds__(256) void gemm_qkv(const bf16* __restrict__ A,
                                                const bf16* __restrict__ Bt,
                                                bf16* __restrict__ QK,
                                                bf16* __restrict__ Vt) {
  __shared__ bf16 lsA[128 * 32];
  __shared__ bf16 lsB[128 * 32];
  const int tid = threadIdx.x, w = tid >> 6, lane = tid & 63;
  const int l15 = lane & 15, quad = lane >> 4;
  const int m0 = blockIdx.x * 128, n0 = blockIdx.y * 128;
  const int wm = (w >> 1) * 64, wn = (w & 1) * 64;
  const int rowA = lane >> 2;
  const int colk = (lane & 3) * 8;

  f32x4 acc[4][4] = {};

  for (int k0 = 0; k0 < 1024; k0 += 32) {
    __syncthreads();
#pragma unroll
    for (int i = 0; i < 2; i++) {
      int s = w * 2 + i;
      const bf16* ga = A + (size_t)(m0 + s * 16 + rowA) * 1024 + k0 + colk;
      GLOAD_LDS16(ga, lsA + s * 512);
      const bf16* gb = Bt + (size_t)(n0 + s * 16 + rowA) * 1024 + k0 + colk;
      GLOAD_LDS16(gb, lsB + s * 512);
    }
    __syncthreads();

    bf16x8 af[4], bfr[4];
#pragma unroll
    for (int r = 0; r < 4; r++)
      af[r] = *(const bf16x8*)(lsA + (wm + r * 16 + l15) * 32 + quad * 8);
#pragma unroll
    for (int c = 0; c < 4; c++)
      bfr[c] = *(const bf16x8*)(lsB + (wn + c * 16 + l15) * 32 + quad * 8);
#pragma unroll
    for (int r = 0; r < 4; r++)
#pragma unroll
      for (int c = 0; c < 4; c++)
        acc[r][c] = MFMA32(af[r], bfr[c], acc[r][c]);
  }

  if (n0 < 2048) {
#pragma unroll
    for (int r = 0; r < 4; r++) {
#pragma unroll
      for (int c = 0; c < 4; c++) {
        int col = n0 + wn + c * 16 + l15;
        float scale = (col < 1024) ? 0.18033688f : 1.0f;  // 0.125*log2e on Q
#pragma unroll
        for (int e = 0; e < 4; e++) {
          int row = m0 + wm + r * 16 + quad * 4 + e;
          QK[(size_t)row * LDQK + col] = (bf16)(acc[r][c][e] * scale);
        }
      }
    }
  } else {
#pragma unroll
    for (int r = 0; r < 4; r++) {
#pragma unroll
      for (int c = 0; c < 4; c++) {
        int vcol = (n0 - 2048) + wn + c * 16 + l15;
        int row0 = m0 + wm + r * 16 + quad * 4;
        bf16x4 pk;
#pragma unroll
        for (int e = 0; e < 4; e++) pk[e] = (bf16)acc[r][c][e];
        *(bf16x4*)(Vt + (size_t)vcol * S_LEN + row0) = pk;
      }
    }
  }
}

// ----------------------------- flash attention -----------------------------
// 1024 blocks, one 64-q tile each; 4 blocks/CU comes from the HW VGPR limit
// (128 VGPR -> 4 waves/EU), NOT from launch_bounds (see round-9 note).
//   head = (i&7) + 8*((i>>3)&1)   -> each XCD holds only 2 heads' K/V in L2
//   qb   = qt<32 ? qt : 95-qt     -> bijective; per-CU tile-work 67±1
// 128-key tiles, 32 keys/wave; K/V/Q frags global->VGPR, register ping-pong.
__global__ __launch_bounds__(256, 2) void flash_attn(const bf16* __restrict__ QK,
                                                     const bf16* __restrict__ Vt,
                                                     bf16* __restrict__ Ctx) {
  __shared__ float Obuf[4][16][68];   // 17.4 KB: per-wave partial O, one qg chunk
  __shared__ float Lbuf[4][4][64];    // 4 KB
  const int tid = threadIdx.x, w = tid >> 6, lane = tid & 63;
  const int l15 = lane & 15, quad = lane >> 4;
  const int i = blockIdx.x;
  const int head = (i & 7) + 8 * ((i >> 3) & 1);
  const int qt_raw = i >> 4;
  const int qb = (qt_raw < 32) ? qt_raw : (95 - qt_raw);
  const int hq = head * HDIM;
  const int krow0 = w * 32 + ((l15 >> 2) << 3) + (l15 & 3);  // permuted key row

  const int T = (qb >> 1) + 1;              // 128-key tiles

  // Q frags (B-operand): q = qb*64 + qg*16 + l15, d = kk*32 + quad*8 + j
  bf16x8 qf[4][2];
#pragma unroll
  for (int qg = 0; qg < 4; qg++)
#pragma unroll
    for (int kk = 0; kk < 2; kk++)
      qf[qg][kk] = *(const bf16x8*)(QK + (size_t)(qb * 64 + qg * 16 + l15) * LDQK +
                                    hq + kk * 32 + quad * 8);

  f32x4 oacc[4][4] = {};
  float lsum[4] = {0.f, 0.f, 0.f, 0.f};

  auto load_k = [&](int j, bf16x8 (&kf)[2][2]) {
#pragma unroll
    for (int c = 0; c < 2; c++)
#pragma unroll
      for (int kk = 0; kk < 2; kk++)
        kf[c][kk] = *(const bf16x8*)(QK + (size_t)(j * 128 + krow0 + 4 * c) * LDQK +
                                     DMODEL + hq + kk * 32 + quad * 8);
  };
  auto load_v = [&](int j, bf16x8 (&vf)[4]) {
#pragma unroll
    for (int dg = 0; dg < 4; dg++)
      vf[dg] = *(const bf16x8*)(Vt + (size_t)(hq + dg * 16 + l15) * S_LEN +
                                j * 128 + w * 32 + quad * 8);
  };
  auto compute = [&](int j, bf16x8 (&kf)[2][2], bf16x8 (&vf)[4]) {
    // S^T = K Q^T : C row = key-slot quad*4+e (matrix c), col = q = l15
    f32x4 sacc[2][4] = {};
#pragma unroll
    for (int kk = 0; kk < 2; kk++)
#pragma unroll
      for (int c = 0; c < 2; c++)
#pragma unroll
        for (int qg = 0; qg < 4; qg++)
          sacc[c][qg] = MFMA32(kf[c][kk], qf[qg][kk], sacc[c][qg]);

    bf16x8 pfr[4];
    if (j == T - 1) {
      const int kb0 = j * 128 + w * 32 + quad * 8;   // + 4c + e = actual key
#pragma unroll
      for (int qg = 0; qg < 4; qg++) {
        const int qrow = qb * 64 + qg * 16 + l15;
        bf16x8 pb;
#pragma unroll
        for (int c = 0; c < 2; c++)
#pragma unroll
          for (int e = 0; e < 4; e++) {
            float s = sacc[c][qg][e];
            if (kb0 + 4 * c + e > qrow) s = -1e30f;
            float pv = __builtin_amdgcn_exp2f(s);
            lsum[qg] += pv;
            pb[c * 4 + e] = (bf16)pv;
          }
        pfr[qg] = pb;
      }
    } else {
#pragma unroll
      for (int qg = 0; qg < 4; qg++) {
        bf16x8 pb;
#pragma unroll
        for (int c = 0; c < 2; c++)
#pragma unroll
          for (int e = 0; e < 4; e++) {
            float pv = __builtin_amdgcn_exp2f(sacc[c][qg][e]);
            lsum[qg] += pv;
            pb[c * 4 + e] = (bf16)pv;
          }
        pfr[qg] = pb;
      }
    }

    // O += P V  (K=32, P direct from registers)
#pragma unroll
    for (int qg = 0; qg < 4; qg++)
#pragma unroll
      for (int dg = 0; dg < 4; dg++)
        oacc[qg][dg] = MFMA32(pfr[qg], vf[dg], oacc[qg][dg]);
  };

  bf16x8 kfA[2][2], vfA[4], kfB[2][2], vfB[4];
  load_k(0, kfA); load_v(0, vfA);
  for (int j = 0; j < T; j += 2) {
    if (j + 1 < T) { load_k(j + 1, kfB); load_v(j + 1, vfB); }
    compute(j, kfA, vfA);
    if (j + 2 < T) { load_k(j + 2, kfA); load_v(j + 2, vfA); }
    if (j + 1 < T) compute(j + 1, kfB, vfB);
  }

  // ---- chunked cross-wave reduction: one qg (16 q-rows) at a time ----
#pragma unroll
  for (int qg = 0; qg < 4; qg++)
    Lbuf[w][quad][qg * 16 + l15] = lsum[qg];

  const int row = tid >> 4;               // 0..15 (local q within chunk)
  const int col = (tid & 15) * 4;         // 0..60 (d within head)
  for (int qg = 0; qg < 4; qg++) {
#pragma unroll
    for (int dg = 0; dg < 4; dg++)
#pragma unroll
      for (int e = 0; e < 4; e++)
        Obuf[w][quad * 4 + e][dg * 16 + l15] = oacc[qg][dg][e];
    __syncthreads();                      // writes visible
    f32x4 os = {};
#pragma unroll
    for (int ww = 0; ww < 4; ww++)
      os += *(const f32x4*)&Obuf[ww][row][col];
    float lr = 0.f;
#pragma unroll
    for (int ww = 0; ww < 4; ww++)
#pragma unroll
      for (int qq = 0; qq < 4; qq++)
        lr += Lbuf[ww][qq][qg * 16 + row];
    const float linv = 1.f / lr;
    bf16x4 ob;
#pragma unroll
    for (int e2 = 0; e2 < 4; e2++) ob[e2] = (bf16)(os[e2] * linv);
    *(bf16x4*)(Ctx + (size_t)(qb * 64 + qg * 16 + row) * DMODEL + hq + col) = ob;
    __syncthreads();                      // reads done before next chunk
  }
}

// ---------------- gemm_out: 64x128 tile, K=1024 -> 512 blocks --------------
__global__ __launch_bounds__(256) void gemm_out(const bf16* __restrict__ A,
                                                const bf16* __restrict__ Bt,
                                                float* __restrict__ C,
                                                const float* __restrict__ bias) {
  __shared__ bf16 lsA[64 * 32];
  __shared__ bf16 lsB[128 * 32];
  const int tid = threadIdx.x, w = tid >> 6, lane = tid & 63;
  const int l15 = lane & 15, quad = lane >> 4;
  const int m0 = blockIdx.x * 64, n0 = blockIdx.y * 128;
  const int wm = (w >> 1) * 32, wn = (w & 1) * 64;
  const int rowA = lane >> 2;
  const int colk = (lane & 3) * 8;

  f32x4 acc[2][4] = {};

  for (int k0 = 0; k0 < 1024; k0 += 32) {
    __syncthreads();
#pragma unroll
    for (int i = 0; i < 3; i++) {
      int s = w * 3 + i;
      if (s < 4) {
        const bf16* ga = A + (size_t)(m0 + s * 16 + rowA) * 1024 + k0 + colk;
        GLOAD_LDS16(ga, lsA + s * 512);
      } else {
        const bf16* gb = Bt + (size_t)(n0 + (s - 4) * 16 + rowA) * 1024 + k0 + colk;
        GLOAD_LDS16(gb, lsB + (s - 4) * 512);
      }
    }
    __syncthreads();

    bf16x8 af[2], bfr[4];
#pragma unroll
    for (int r = 0; r < 2; r++)
      af[r] = *(const bf16x8*)(lsA + (wm + r * 16 + l15) * 32 + quad * 8);
#pragma unroll
    for (int c = 0; c < 4; c++)
      bfr[c] = *(const bf16x8*)(lsB + (wn + c * 16 + l15) * 32 + quad * 8);
#pragma unroll
    for (int r = 0; r < 2; r++)
#pragma unroll
      for (int c = 0; c < 4; c++)
        acc[r][c] = MFMA32(af[r], bfr[c], acc[r][c]);
  }

#pragma unroll
  for (int r = 0; r < 2; r++) {
#pragma unroll
    for (int c = 0; c < 4; c++) {
      int col = n0 + wn + c * 16 + l15;
#pragma unroll
      for (int e = 0; e < 4; e++) {
        int row = m0 + wm + r * 16 + quad * 4 + e;
        C[(size_t)row * 1024 + col] = acc[r][c][e] + bias[col];
      }
    }
  }
}

// ------------------------------- launcher ----------------------------------
extern "C" void kernel_launch(void* const* d_in, const int* in_sizes, int n_in,
                              void* d_out, int out_size, void* d_ws, size_t ws_size,
                              hipStream_t stream) {
  const float* x  = (const float*)d_in[0];
  const float* Wq = (const float*)d_in[1];
  const float* Wk = (const float*)d_in[2];
  const float* Wv = (const float*)d_in[3];
  const float* Wo = (const float*)d_in[4];
  const float* bo = (const float*)d_in[5];

  char* ws = (char*)d_ws;                    // 48 MB total
  bf16* xb  = (bf16*)(ws);                   // 8 MB  [4096][1024]
  bf16* Wt  = (bf16*)(ws + (8u  << 20));     // 6 MB  [3072][1024]
  bf16* Wot = (bf16*)(ws + (14u << 20));     // 2 MB  [1024][1024]
  bf16* QK  = (bf16*)(ws + (16u << 20));     // 16 MB [4096][2048]
  bf16* Vt  = (bf16*)(ws + (32u << 20));     // 8 MB  [1024][4096]
  bf16* Ctx = (bf16*)(ws + (40u << 20));     // 8 MB  [4096][1024]

  preprocess<<<2048, 256, 0, stream>>>(x, Wq, Wk, Wv, Wo, xb, Wt, Wot);
  gemm_qkv<<<dim3(32, 24), 256, 0, stream>>>(xb, Wt, QK, Vt);
  flash_attn<<<1024, 256, 0, stream>>>(QK, Vt, Ctx);
  gemm_out<<<dim3(64, 8), 256, 0, stream>>>(Ctx, Wot, (float*)d_out, bo);
}